// Round 5
// baseline (396.945 us; speedup 1.0000x reference)
//
#include <hip/hip_runtime.h>
#include <hip/hip_bf16.h>

// Encoder layer. fp32 in/out, bf16 MFMA compute, fp32 accum.
// B=16 S=512 H=768 A=12 DH=64 F=3072.
// Round 15: gemm_8ph — faithful m201 8-phase port (32x32x16 shape) for
// QKV + FFN1. Diagnosis r13/r14: every 1-block/CU structure that issues
// the 64KB tile stage as ONE burst + drain lands at 420-530 TF (7300
// cyc/tile vs ~2000 accountable) — chip-wide lockstep burst/drain. The
// 8-phase fix: 2 glds per phase (even issue rate), counted vmcnt(4) only
// at phases 4/8 referencing loads >=4 phases old, per-phase barrier pairs.
// WAR safety: LDS units freed quadrant-wise; stage of tile T+2's unit
// lands >=1 phase after tile T's last read of that unit:
//   p1:A1(T+1) p2:B1(T+1) p3:A0(T+2) p4:B0(T+2)+vmcnt(4)
//   p5:A1(T+2) p6:B1(T+2) p7:A0(T+3) p8:B0(T+3)+vmcnt(4)
// A-buffer rows permuted mh-major, B-buffer ni-major so each unit is 128
// contiguous rows = 2 linear glds passes. B-frags held in regs (24
// ds_read_b128/tile = minimum). O-proj/FFN2 stay on gemm128 (N=768).

using bf16_t = __hip_bfloat16;
typedef __bf16 bf16x8 __attribute__((ext_vector_type(8)));
typedef float f32x4 __attribute__((ext_vector_type(4)));
typedef float f32x16 __attribute__((ext_vector_type(16)));

__device__ __forceinline__ float b2f(bf16_t v) { return __bfloat162float(v); }
__device__ __forceinline__ bf16_t f2b(float v) { return __float2bfloat16(v); }
__device__ __forceinline__ ushort f2bu(float v) { bf16_t b = f2b(v); return *(ushort*)&b; }

// async global->LDS 16B copy (dest = wave base + lane*16 by construction)
__device__ __forceinline__ void glds16(const ushort* g, ushort* l) {
    __builtin_amdgcn_global_load_lds(
        (const __attribute__((address_space(1))) unsigned int*)g,
        (__attribute__((address_space(3))) unsigned int*)l, 16, 0, 0);
}

// tanh-form GELU (overflow-safe), |err vs exact| ~1e-3 << 0.102 threshold
__device__ __forceinline__ float gelu_f(float x) {
    float x2 = x * x;
    float y2 = 1.5957691216057308f * x * fmaf(0.044715f, x2, 1.0f);
    float e = __expf(y2);
    float t = 1.f - 2.f / (e + 1.f);
    return 0.5f * x * (1.f + t);
}

// ---------------------------------------------------------------------------
// Prep mega-kernel: 6 weight transposes + bias concat + X cast. One launch.
// ---------------------------------------------------------------------------
__device__ __forceinline__ void tr_tile(const float* __restrict__ in,
                                        bf16_t* __restrict__ out,
                                        int R, int C, int tx, int ty,
                                        float (*t)[65], int tid)
{
    int r0 = ty * 64, c0 = tx * 64;
    int tr = tid >> 6, tc = tid & 63;
#pragma unroll 4
    for (int i = 0; i < 16; ++i) {
        int r = i * 4 + tr;
        t[r][tc] = in[(size_t)(r0 + r) * C + c0 + tc];
    }
    __syncthreads();
#pragma unroll 4
    for (int i = 0; i < 16; ++i) {
        int r = i * 4 + tr;
        out[(size_t)(c0 + r) * R + r0 + tc] = f2b(t[tc][r]);
    }
}

__global__ __launch_bounds__(256) void prep_kernel(
    const float* __restrict__ WQ, const float* __restrict__ WK,
    const float* __restrict__ WV, const float* __restrict__ WO,
    const float* __restrict__ W1, const float* __restrict__ W2,
    const float* __restrict__ bQ, const float* __restrict__ bK,
    const float* __restrict__ bV, const float* __restrict__ X,
    bf16_t* __restrict__ Wqkv, bf16_t* __restrict__ WOt,
    bf16_t* __restrict__ W1t, bf16_t* __restrict__ W2t,
    float* __restrict__ bcat, bf16_t* __restrict__ Xb)
{
    __shared__ float t[64][65];
    const int blk = blockIdx.x, tid = threadIdx.x;
    if (blk < 576) {
        int m = blk / 144, tt = blk % 144;
        const float* in = (m == 0) ? WQ : (m == 1) ? WK : (m == 2) ? WV : WO;
        bf16_t* out = (m == 0) ? Wqkv : (m == 1) ? Wqkv + 589824
                    : (m == 2) ? Wqkv + 1179648 : WOt;
        tr_tile(in, out, 768, 768, tt % 12, tt / 12, t, tid);
    } else if (blk < 1152) {
        int tt = blk - 576;
        tr_tile(W1, W1t, 768, 3072, tt % 48, tt / 48, t, tid);
    } else if (blk < 1728) {
        int tt = blk - 1152;
        tr_tile(W2, W2t, 3072, 768, tt % 12, tt / 12, t, tid);
    } else if (blk == 1728) {
        for (int i = tid; i < 2304; i += 256)
            bcat[i] = (i < 768) ? bQ[i] : (i < 1536) ? bK[i - 768] : bV[i - 1536];
    } else {
        size_t i = ((size_t)(blk - 1729) * 256 + tid) * 8;
        float4 a = *(const float4*)(X + i);
        float4 b = *(const float4*)(X + i + 4);
#pragma unroll
        for (int j = 0; j < 4; ++j) {
            Xb[i + j]     = f2b(((const float*)&a)[j]);
            Xb[i + 4 + j] = f2b(((const float*)&b)[j]);
        }
    }
}

// ---------------------------------------------------------------------------
// gemm_8ph: NT GEMM, 256x256 tile, BK=64, 512 thr = 8 waves (2Mx4N, wave
// 128x64, acc[4][2]). 8-phase schedule, see header. Requires nk even, >=4.
// LDS 128 KiB: even tile at [0] (A) / [16384] (B) ushorts, odd at +32768.
// A-buf row ar: global m = m0 + wrbit(ar6)*128 + mh(ar7)*64 + (ar&63);
//   frag (wr,mi,l31) -> ar = mh*128 + wr*64 + (mi&1)*32 + l31.
// B-buf row br: global n = n0 + ((br>>5)&3)*64 + (br>>7)*32 + (br&31);
//   frag (wc,ni,l31) -> br = ni*128 + wc*32 + l31.
// Swizzle (proven): phys chunk = (kk*2+khalf) ^ (bufrow&7); source column
// pre-swizzled at stage. EPI: 1 bias+GELU->bf16 | 6 segmented QKV.
// ---------------------------------------------------------------------------
template <int EPI>
__global__ __launch_bounds__(512, 1) void gemm_8ph(
    const bf16_t* __restrict__ A, const bf16_t* __restrict__ Bt,
    const float* __restrict__ bias, const void* __restrict__ res,
    void* __restrict__ Cv, int K, int lda, int ldb, int ldc)
{
    extern __shared__ ushort lds[];   // 65536 ushorts = 128 KiB
    const int tid = threadIdx.x;
    const int l31 = tid & 31, khalf = (tid >> 5) & 1;
    const int w = tid >> 6;
    const int wr = w >> 2, wc = w & 3;      // 2M x 4N, wave tile 128x64
    const int m0 = blockIdx.x * 256, n0 = blockIdx.y * 256;

    // ---- stage source pointers (permuted rows, pre-swizzled columns) ----
    const int s = tid >> 3;                     // 0..63: row within pass
    const int c = (((tid & 7) ^ (s & 7)) << 3); // pre-swizzled chunk (ushorts)
    const ushort* pA[4];
    pA[0] = (const ushort*)A + (size_t)(m0 + s)       * lda + c;   // ar   0- 63
    pA[1] = (const ushort*)A + (size_t)(m0 + 128 + s) * lda + c;   // ar  64-127
    pA[2] = (const ushort*)A + (size_t)(m0 + 64 + s)  * lda + c;   // ar 128-191
    pA[3] = (const ushort*)A + (size_t)(m0 + 192 + s) * lda + c;   // ar 192-255
    const int nbs = ((s >> 5) << 6) + (s & 31);
    const ushort* pB[4];
    pB[0] = (const ushort*)Bt + (size_t)(n0 + nbs)        * ldb + c;  // br   0- 63
    pB[1] = (const ushort*)Bt + (size_t)(n0 + 128 + nbs)  * ldb + c;  // br  64-127
    pB[2] = (const ushort*)Bt + (size_t)(n0 + nbs + 32)   * ldb + c;  // br 128-191
    pB[3] = (const ushort*)Bt + (size_t)(n0 + 128 + nbs + 32) * ldb + c;
    const int dOff = tid * 8;

    f32x16 acc[4][2] = {};
    const int nk = K >> 6;                  // even, >= 4

    // unit u of a tile = buffer rows [u*128, u*128+128) = 2 glds passes
    auto SA = [&](int bo, int u, int kt) {
        ushort* d = lds + bo + u * 8192 + dOff;
        glds16(pA[2 * u]     + (size_t)kt * 64, d);
        glds16(pA[2 * u + 1] + (size_t)kt * 64, d + 4096);
    };
    auto SB = [&](int bo, int u, int kt) {
        ushort* d = lds + bo + 16384 + u * 8192 + dOff;
        glds16(pB[2 * u]     + (size_t)kt * 64, d);
        glds16(pB[2 * u + 1] + (size_t)kt * 64, d + 4096);
    };

    bf16x8 a[8], b0[4], b1[4];
    auto RDA = [&](int mh, int bo) {
#pragma unroll
        for (int m2 = 0; m2 < 2; ++m2)
#pragma unroll
            for (int kk = 0; kk < 4; ++kk) {
                int ar = mh * 128 + wr * 64 + m2 * 32 + l31;
                a[m2 * 4 + kk] = *(const bf16x8*)&lds[bo + ar * 64 + (((kk * 2 + khalf) ^ (l31 & 7)) << 3)];
            }
    };
    auto RDB = [&](int ni, int bo, bf16x8* b) {
        int br = ni * 128 + wc * 32 + l31;
#pragma unroll
        for (int kk = 0; kk < 4; ++kk)
            b[kk] = *(const bf16x8*)&lds[bo + 16384 + br * 64 + (((kk * 2 + khalf) ^ (l31 & 7)) << 3)];
    };
    auto MM = [&](int mh, int ni, bf16x8* b) {
#pragma unroll
        for (int kk = 0; kk < 4; ++kk) {   // SWAPPED: D lane=m, regs=n
            acc[mh * 2 + 0][ni] = __builtin_amdgcn_mfma_f32_32x32x16_bf16(b[kk], a[kk],     acc[mh * 2 + 0][ni], 0, 0, 0);
            acc[mh * 2 + 1][ni] = __builtin_amdgcn_mfma_f32_32x32x16_bf16(b[kk], a[4 + kk], acc[mh * 2 + 1][ni], 0, 0, 0);
        }
    };

#define PH_SYNC() do { __builtin_amdgcn_s_barrier(); \
    asm volatile("s_waitcnt lgkmcnt(0)" ::: "memory"); \
    __builtin_amdgcn_sched_barrier(0); \
    __builtin_amdgcn_s_setprio(1); } while (0)
#define PH_END() do { __builtin_amdgcn_s_setprio(0); \
    __builtin_amdgcn_s_barrier(); } while (0)

    // prologue: tile0 all units + tile1 A0,B0 (12 glds); wait tile0 (oldest 8)
    SA(0, 0, 0); SB(0, 0, 0); SA(0, 1, 0); SB(0, 1, 0);
    SA(32768, 0, 1); SB(32768, 0, 1);
    asm volatile("s_waitcnt vmcnt(4)" ::: "memory");
    __builtin_amdgcn_s_barrier();

    for (int T = 0; T < nk; T += 2) {
        const bool n2 = (T + 2) < nk;       // nk even -> (T+3<nk) == n2
        // ---- tile T (even buffer) ----
        SA(32768, 1, T + 1);                                 // p1
        RDA(0, 0); RDB(0, 0, b0);
        PH_SYNC(); MM(0, 0, b0); PH_END();
        SB(32768, 1, T + 1);                                 // p2
        RDB(1, 0, b1);
        PH_SYNC(); MM(0, 1, b1); PH_END();
        if (n2) SA(0, 0, T + 2);                             // p3
        RDA(1, 0);
        PH_SYNC(); MM(1, 0, b0); PH_END();
        if (n2) SB(0, 0, T + 2);                             // p4
        __builtin_amdgcn_s_barrier();
        asm volatile("s_waitcnt lgkmcnt(0)" ::: "memory");
        __builtin_amdgcn_sched_barrier(0);
        __builtin_amdgcn_s_setprio(1); MM(1, 1, b1); __builtin_amdgcn_s_setprio(0);
        if (n2) asm volatile("s_waitcnt vmcnt(4)" ::: "memory");
        else    asm volatile("s_waitcnt vmcnt(0)" ::: "memory");
        __builtin_amdgcn_s_barrier();
        // ---- tile T+1 (odd buffer) ----
        if (n2) SA(0, 1, T + 2);                             // p5
        RDA(0, 32768); RDB(0, 32768, b0);
        PH_SYNC(); MM(0, 0, b0); PH_END();
        if (n2) SB(0, 1, T + 2);                             // p6
        RDB(1, 32768, b1);
        PH_SYNC(); MM(0, 1, b1); PH_END();
        if (n2) SA(32768, 0, T + 3);                         // p7
        RDA(1, 32768);
        PH_SYNC(); MM(1, 0, b0); PH_END();
        if (n2) SB(32768, 0, T + 3);                         // p8
        __builtin_amdgcn_s_barrier();
        asm volatile("s_waitcnt lgkmcnt(0)" ::: "memory");
        __builtin_amdgcn_sched_barrier(0);
        __builtin_amdgcn_s_setprio(1); MM(1, 1, b1); __builtin_amdgcn_s_setprio(0);
        if (n2) asm volatile("s_waitcnt vmcnt(4)" ::: "memory");
        __builtin_amdgcn_s_barrier();
    }
#undef PH_SYNC
#undef PH_END

    // Epilogue: m = m0 + wr*128 + mi*32 + l31; reg g*4+r -> n = n0 + wc*64 + ni*32 + 8g + 4khalf + r
#pragma unroll
    for (int mi = 0; mi < 4; ++mi) {
        int m = m0 + wr * 128 + mi * 32 + l31;
#pragma unroll
        for (int ni = 0; ni < 2; ++ni) {
#pragma unroll
            for (int g = 0; g < 4; ++g) {
                int nb = n0 + wc * 64 + ni * 32 + 8 * g + 4 * khalf;
                float4 bv4 = *(const float4*)&bias[nb];
                float v[4];
#pragma unroll
                for (int r = 0; r < 4; ++r) v[r] = acc[mi][ni][g * 4 + r] + ((const float*)&bv4)[r];
                if constexpr (EPI == 1) {
#pragma unroll
                    for (int r = 0; r < 4; ++r) v[r] = gelu_f(v[r]);
                }
                ushort4 st;
                st.x = f2bu(v[0]); st.y = f2bu(v[1]); st.z = f2bu(v[2]); st.w = f2bu(v[3]);
                if constexpr (EPI == 6) {
                    int seg = n0 / 768;      // block-uniform (n0 % 768 in {0,256,512})
                    int nloc = (n0 % 768) + wc * 64 + ni * 32 + 8 * g + 4 * khalf;
                    if (seg < 2) {
                        bf16_t* Cseg = (bf16_t*)Cv + (size_t)seg * 6291456;
                        *(ushort4*)&((ushort*)Cseg)[(size_t)m * 768 + nloc] = st;
                    } else {
                        // V segment -> Vt[h][d][s'] via faithful flat reshape
                        ushort* vt = (ushort*)res;
                        int fb = (m & 511) * 768 + nloc;
                        int h = (m >> 9) * 12 + (fb >> 15);
                        int d = fb & 63;
                        int sx = (fb >> 6) & 511;
                        ushort* vh = vt + (size_t)h * 32768 + sx;
                        vh[(size_t)(d + 0) * 512] = st.x;
                        vh[(size_t)(d + 1) * 512] = st.y;
                        vh[(size_t)(d + 2) * 512] = st.z;
                        vh[(size_t)(d + 3) * 512] = st.w;
                    }
                } else {
                    *(ushort4*)&((ushort*)Cv)[(size_t)m * ldc + nb] = st;
                }
            }
        }
    }
}

// ---------------------------------------------------------------------------
// NT GEMM, BK=64, swapped-operand mfma_f32_32x32x16_bf16 (round-10 proven
// kernel: O-proj (EPI 2), FFN2 (EPI 5)). Tile 128 x NTILE x 64, 4 waves.
// ---------------------------------------------------------------------------
template <int EPI, int NTILE>
__global__ __launch_bounds__(256) void gemm128(
    const bf16_t* __restrict__ A, const bf16_t* __restrict__ Bt,
    const float* __restrict__ bias, const void* __restrict__ res,
    void* __restrict__ Cv, int K, int lda, int ldb, int ldc)
{
    __shared__ ushort lA[128 * 64];
    __shared__ ushort lB[NTILE * 64];
    constexpr int NI = NTILE / 64;           // 32x32 n-subtiles per wave
    const int tid = threadIdx.x;
    const int l = tid & 63, w = tid >> 6;
    const int l31 = l & 31, khalf = l >> 5;  // frag row / k-half
    const int m0 = blockIdx.x * 128, n0 = blockIdx.y * NTILE;

    const int srow = tid >> 3;
    const int sg = (((tid & 7) ^ (srow & 7)) << 3);
    const ushort* gA = (const ushort*)A + (size_t)(m0 + srow) * lda + sg;
    const ushort* gB = (const ushort*)Bt + (size_t)(n0 + srow) * ldb + sg;
    ushort* dA = lA + tid * 8;
    ushort* dB = lB + tid * 8;

    f32x16 acc[2][NI] = {};
    const int arow = (w & 1) * 64;
    const int brow = (w >> 1) * (NTILE / 2);

    for (int k0 = 0; k0 < K; k0 += 64) {
        __syncthreads();
        glds16(gA + k0,                      dA);
        glds16(gA + k0 + (size_t)32 * lda,   dA + 2048);
        glds16(gA + k0 + (size_t)64 * lda,   dA + 4096);
        glds16(gA + k0 + (size_t)96 * lda,   dA + 6144);
        glds16(gB + k0,                      dB);
        glds16(gB + k0 + (size_t)32 * ldb,   dB + 2048);
        if constexpr (NTILE == 128) {
            glds16(gB + k0 + (size_t)64 * ldb, dB + 4096);
            glds16(gB + k0 + (size_t)96 * ldb, dB + 6144);
        }
        __syncthreads();
#pragma unroll
        for (int kk = 0; kk < 4; ++kk) {
            const int pc = (((kk * 2 + khalf) ^ (l31 & 7)) << 3);
            bf16x8 bfr[NI];
#pragma unroll
            for (int ni = 0; ni < NI; ++ni)
                bfr[ni] = *(const bf16x8*)&lB[(brow + ni * 32 + l31) * 64 + pc];
#pragma unroll
            for (int mi = 0; mi < 2; ++mi) {
                bf16x8 afr = *(const bf16x8*)&lA[(arow + mi * 32 + l31) * 64 + pc];
#pragma unroll
                for (int ni = 0; ni < NI; ++ni)   // SWAPPED: D lane=m, regs=n
                    acc[mi][ni] = __builtin_amdgcn_mfma_f32_32x32x16_bf16(bfr[ni], afr, acc[mi][ni], 0, 0, 0);
            }
        }
    }

    // Epilogue: m = arow + mi*32 + l31; reg g*4+r -> n = ni*32 + 8g + 4*khalf + r
#pragma unroll
    for (int mi = 0; mi < 2; ++mi) {
        int m = m0 + arow + mi * 32 + l31;
#pragma unroll
        for (int ni = 0; ni < NI; ++ni) {
#pragma unroll
            for (int g = 0; g < 4; ++g) {
                int nb = n0 + brow + ni * 32 + 8 * g + 4 * khalf;  // 4 consecutive n
                float4 bv4 = *(const float4*)&bias[nb];
                float v[4];
#pragma unroll
                for (int r = 0; r < 4; ++r) v[r] = acc[mi][ni][g * 4 + r] + ((const float*)&bv4)[r];
                if constexpr (EPI == 1) {
#pragma unroll
                    for (int r = 0; r < 4; ++r) v[r] = gelu_f(v[r]);
                } else if constexpr (EPI == 2) {
                    float4 r4 = *(const float4*)&((const float*)res)[(size_t)m * ldc + nb];
#pragma unroll
                    for (int r = 0; r < 4; ++r) v[r] += ((const float*)&r4)[r];
                } else if constexpr (EPI == 5) {
                    ushort4 rb = *(const ushort4*)&((const ushort*)res)[(size_t)m * ldc + nb];
#pragma unroll
                    for (int r = 0; r < 4; ++r) v[r] += b2f(*(const bf16_t*)&((const ushort*)&rb)[r]);
                }
                if constexpr (EPI == 5) {
                    *(float4*)&((float*)Cv)[(size_t)m * ldc + nb] = make_float4(v[0], v[1], v[2], v[3]);
                } else {
                    ushort4 st;
                    st.x = f2bu(v[0]); st.y = f2bu(v[1]); st.z = f2bu(v[2]); st.w = f2bu(v[3]);
                    *(ushort4*)&((ushort*)Cv)[(size_t)m * ldc + nb] = st;
                }
            }
        }
    }
}

// ---------------------------------------------------------------------------
// Flash attention, Q-tile 128, swapped-operand 16x16x32 MFMA (round-9 verified).
// ---------------------------------------------------------------------------
__global__ __launch_bounds__(256) void flash_kernel(
    const bf16_t* __restrict__ Q, const bf16_t* __restrict__ Kx,
    const bf16_t* __restrict__ Vt, const int* __restrict__ mask,
    bf16_t* __restrict__ Z)
{
    __shared__ ushort lK[64 * 64];
    __shared__ ushort lV[64 * 64];
    __shared__ ushort lP[128 * 72];

    const int h = blockIdx.y;
    const int q0 = blockIdx.x * 128;
    const ushort* Qh = (const ushort*)Q + (size_t)h * 32768;
    const ushort* Kh = (const ushort*)Kx + (size_t)h * 32768;
    const ushort* Vh = (const ushort*)Vt + (size_t)h * 32768;   // [64][512]
    const int* mk = mask + (h / 12) * 512;
    ushort* Zh = (ushort*)Z + (size_t)h * 32768;

    const int tid = threadIdx.x;
    const int l = tid & 63, w = tid >> 6;
    const int l16 = l & 15, quad = l >> 4;

    bf16x8 qfr[2][2];   // [mi][kk]
#pragma unroll
    for (int mi = 0; mi < 2; ++mi)
#pragma unroll
        for (int kk = 0; kk < 2; ++kk)
            qfr[mi][kk] = *(const bf16x8*)(Qh + (size_t)(q0 + w * 32 + mi * 16 + l16) * 64 + kk * 32 + quad * 8);

    const int c8p = tid & 7;
    const int kr0 = tid >> 3;
    float m_i[2] = {-1e30f, -1e30f}, l_i[2] = {0.f, 0.f};
    f32x4 o4[2][4] = {};

    for (int kt = 0; kt < 8; ++kt) {
#pragma unroll
        for (int p = 0; p < 2; ++p) {
            int row = kr0 + p * 32;
            int c8l = c8p ^ (row & 7);
            glds16(Kh + (size_t)(kt * 64 + row) * 64 + c8l * 8, lK + (p * 256 + tid) * 8);
            glds16(Vh + (size_t)row * 512 + kt * 64 + c8l * 8, lV + (p * 256 + tid) * 8);
        }
        __syncthreads();

        f32x4 s4[2][4] = {};
#pragma unroll
        for (int kk = 0; kk < 2; ++kk) {
#pragma unroll
            for (int nt = 0; nt < 4; ++nt) {
                bf16x8 kfr = *(const bf16x8*)&lK[(nt * 16 + l16) * 64 + (((kk * 4 + quad) ^ (l16 & 7)) << 3)];
#pragma unroll
                for (int mi = 0; mi < 2; ++mi)
                    s4[mi][nt] = __builtin_amdgcn_mfma_f32_16x16x32_bf16(kfr, qfr[mi][kk], s4[mi][nt], 0, 0, 0);
            }
        }

        int4 m4[4];
#pragma unroll
        for (int nt = 0; nt < 4; ++nt) m4[nt] = *(const int4*)&mk[kt * 64 + nt * 16 + quad * 4];

#pragma unroll
        for (int mi = 0; mi < 2; ++mi) {
            float pv[4][4];
            float rm = -1e30f;
#pragma unroll
            for (int nt = 0; nt < 4; ++nt)
#pragma unroll
                for (int r = 0; r < 4; ++r) {
                    float v = (((const int*)&m4[nt])[r] == 0) ? -1e30f : s4[mi][nt][r] * 0.125f;
                    pv[nt][r] = v;
                    rm = fmaxf(rm, v);
                }
            rm = fmaxf(rm, __shfl_xor(rm, 16));
            rm = fmaxf(rm, __shfl_xor(rm, 32));
            float mn = fmaxf(m_i[mi], rm);
            float al = __expf(m_i[mi] - mn);
            float rs = 0.f;
#pragma unroll
            for (int nt = 0; nt < 4; ++nt)
#pragma unroll
                for (int r = 0; r < 4; ++r) {
                    float e = __expf(pv[nt][r] - mn);
                    pv[nt][r] = e;
                    rs += e;
                }
            rs += __shfl_xor(rs, 16);
            rs += __shfl_xor(rs, 32);
            l_i[mi] = l_i[mi] * al + rs;
            m_i[mi] = mn;
#pragma unroll
            for (int dt = 0; dt < 4; ++dt)
#pragma unroll
                for (int r = 0; r < 4; ++r) o4[mi][dt][r] *= al;

#pragma unroll
            for (int nt = 0; nt < 4; ++nt) {
                ushort4 st;
                st.x = f2bu(pv[nt][0]); st.y = f2bu(pv[nt][1]);
                st.z = f2bu(pv[nt][2]); st.w = f2bu(pv[nt][3]);
                *(ushort4*)&lP[(w * 32 + mi * 16 + l16) * 72 + nt * 16 + quad * 4] = st;
            }
        }
        __syncthreads();

#pragma unroll
        for (int kk = 0; kk < 2; ++kk) {
#pragma unroll
            for (int dt = 0; dt < 4; ++dt) {
                bf16x8 bvfr = *(const bf16x8*)&lV[(dt * 16 + l16) * 64 + (((kk * 4 + quad) ^ (l16 & 7)) << 3)];
#pragma unroll
                for (int mi = 0; mi < 2; ++mi) {
                    bf16x8 pafr = *(const bf16x8*)&lP[(w * 32 + mi * 16 + l16) * 72 + kk * 32 + quad * 8];
                    o4[mi][dt] = __builtin_amdgcn_mfma_f32_16x16x32_bf16(bvfr, pafr, o4[mi][dt], 0, 0, 0);
                }
            }
        }
        __syncthreads();
    }

#pragma unroll
    for (int mi = 0; mi < 2; ++mi) {
        float inv = 1.f / l_i[mi];
#pragma unroll
        for (int dt = 0; dt < 4; ++dt) {
            ushort4 st;
            st.x = f2bu(o4[mi][dt][0] * inv); st.y = f2bu(o4[mi][dt][1] * inv);
            st.z = f2bu(o4[mi][dt][2] * inv); st.w = f2bu(o4[mi][dt][3] * inv);
            *(ushort4*)&Zh[(size_t)(q0 + w * 32 + mi * 16 + l16) * 64 + dt * 16 + quad * 4] = st;
        }
    }
}

// ---------------------------------------------------------------------------
// LayerNorm over H=768, one block per row, fp32 stats. In-place safe.
// ---------------------------------------------------------------------------
__device__ __forceinline__ float to_f(float v)  { return v; }
__device__ __forceinline__ float to_f(bf16_t v) { return b2f(v); }
__device__ __forceinline__ void from_f(float& d, float v)  { d = v; }
__device__ __forceinline__ void from_f(bf16_t& d, float v) { d = f2b(v); }

template <typename TI, typename TO>
__global__ __launch_bounds__(256) void layernorm_kernel(
    const TI* __restrict__ X, const float* __restrict__ w,
    const float* __restrict__ b, TO* __restrict__ out)
{
    const TI* x = X + (size_t)blockIdx.x * 768;
    TO* o = out + (size_t)blockIdx.x * 768;
    int t = threadIdx.x;
    float v[3];
    float s = 0.f, sq = 0.f;
#pragma unroll
    for (int i = 0; i < 3; ++i) {
        v[i] = to_f(x[t + i * 256]);
        s += v[i]; sq += v[i] * v[i];
    }
#pragma unroll
    for (int off = 32; off; off >>= 1) { s += __shfl_xor(s, off); sq += __shfl_xor(sq, off); }
    __shared__ float s1[4], s2[4];
    int wave = t >> 6, lane = t & 63;
    if (lane == 0) { s1[wave] = s; s2[wave] = sq; }
    __syncthreads();
    s  = s1[0] + s1[1] + s1[2] + s1[3];
    sq = s2[0] + s2[1] + s2[2] + s2[3];
    float mu  = s * (1.f / 768.f);
    float var = sq * (1.f / 768.f) - mu * mu;
    float rs  = rsqrtf(var + 1e-5f);
#pragma unroll
    for (int i = 0; i < 3; ++i)
        from_f(o[t + i * 256], (v[i] - mu) * rs * w[t + i * 256] + b[t + i * 256]);
}

// ---------------------------------------------------------------------------
extern "C" void kernel_launch(void* const* d_in, const int* in_sizes, int n_in,
                              void* d_out, int out_size, void* d_ws, size_t ws_size,
                              hipStream_t stream)
{
    const float* X    = (const float*)d_in[0];
    const int*   mask = (const int*)  d_in[1];
    const float* WQ   = (const float*)d_in[2];
    const float* bQ   = (const float*)d_in[3];
    const float* WK   = (const float*)d_in[4];
    const float* bK   = (const float*)d_in[5];
    const float* WV   = (const float*)d_in[6];
    const float* bV   = (const float*)d_in[7];
    const float* WO   = (const float*)d_in[8];
    const float* bO   = (const float*)d_in[9];
    const float* ln1w = (const float*)d_in[10];
    const float* ln1b = (const float*)d_in[11];
    const float* W1   = (const float*)d_in[12];
    const float* b1   = (const float*)d_in[13];
    const float* W2   = (const float*)d_in[14];
    const float* b2   = (const float*)d_in[15];
    const float* ln2w = (const float*)d_in[16];
    const float* ln2b = (const float*)d_in[17];
    float* out = (float*)d_out;

    // ---- workspace (bf16 elems; total 38,539,776 = 77.1 MB) ----
    bf16_t* ws   = (bf16_t*)d_ws;
    bf16_t* Wqkv = ws;                        // [2304][768] (WQt|WKt|WVt)
    bf16_t* WOt  = Wqkv + 1769472;            // [768][768]
    bf16_t* W1t  = WOt + 589824;              // [3072][768]
    bf16_t* W2t  = W1t + 2359296;             // [768][3072]
    float*  bcat = (float*)(W2t + 2359296);   // fp32[2304] (= 4608 bf16)
    bf16_t* Qb   = W2t + 2359296 + 4608;      // packed [8192][768]; Q,K consecutive (EPI 6)
    bf16_t* Kb   = Qb + 6291456;
    bf16_t* Vb   = Kb + 6291456;              // (layout hold)
    bf16_t* Xb   = Vb + 6291456;              // bf16 X (dead after QKV; Y1 alias)
    bf16_t* Vt   = Xb + 6291456;              // per-head V^T [192][64][512], from QKV epilogue
    // aliases (dead-before-write):
    bf16_t* Zb = Qb;   // flash writes Z in-place over Q
    bf16_t* Y1 = Xb;   // O-proj out (Xb dead after QKV gemm)
    bf16_t* X1 = Qb;   // LN1 out (Qb/Z dead after O-proj)
    bf16_t* Hb = Kb;   // FFN mid [8192][3072] = Kb+Vb+Xb+Vt exactly

    // allow 128 KiB dynamic LDS for gemm_8ph (host-side attribute, capture-safe)
    (void)hipFuncSetAttribute(reinterpret_cast<const void*>(&gemm_8ph<6>),
                              hipFuncAttributeMaxDynamicSharedMemorySize, 131072);
    (void)hipFuncSetAttribute(reinterpret_cast<const void*>(&gemm_8ph<1>),
                              hipFuncAttributeMaxDynamicSharedMemorySize, 131072);

    // ---- 1. prep ----
    prep_kernel<<<4801, 256, 0, stream>>>(WQ, WK, WV, WO, W1, W2, bQ, bK, bV, X,
                                          Wqkv, WOt, W1t, W2t, bcat, Xb);

    // ---- 2. fused QKV projection -> packed Q/K + transposed Vt (8-phase) ----
    gemm_8ph<6><<<dim3(32, 9), 512, 131072, stream>>>(Xb, Wqkv, bcat, Vt, Qb,
                                                      768, 768, 768, 768);

    // ---- 3. flash attention (Q-tile 128), Z in-place over Q ----
    flash_kernel<<<dim3(4, 192), 256, 0, stream>>>(Qb, Kb, Vt, mask, Zb);

    // ---- 4. O-projection + fp32 residual -> Y1, LN1 -> X1 (r10 path) ----
    gemm128<2, 64><<<dim3(64, 12), 256, 0, stream>>>(Zb, WOt, bO, X, Y1,
                                                     768, 768, 768, 768);
    layernorm_kernel<bf16_t, bf16_t><<<8192, 256, 0, stream>>>(Y1, ln1w, ln1b, X1);

    // ---- 5. FFN: FFN1 on the 8-phase kernel ----
    gemm_8ph<1><<<dim3(32, 12), 512, 131072, stream>>>(X1, W1t, b1, nullptr, Hb,
                                                       768, 768, 768, 3072);
    gemm128<5, 64><<<dim3(64, 12), 256, 0, stream>>>(Hb, W2t, b2, X1, out,
                                                     3072, 3072, 3072, 768);
    layernorm_kernel<float, float><<<8192, 256, 0, stream>>>(out, ln2w, ln2b, out);
}

// Round 6
// 359.935 us; speedup vs baseline: 1.1028x; 1.1028x over previous
//
#include <hip/hip_runtime.h>
#include <hip/hip_bf16.h>

// Encoder layer. fp32 in/out, bf16 MFMA compute, fp32 accum.
// B=16 S=512 H=768 A=12 DH=64 F=3072.
// Round 16: GEMM schedule line closed (5 structures, all 65-81 us on FFN1;
// gemm128 w/ 6 blocks/CU is empirically best at these shapes). Config
// restored to round-10 everywhere. Flash upgraded 16x16x32 -> 32x32x16
// (swapped operands), iso-structure: same staging/swizzle/barriers/P-LDS,
// but -17% matrix-pipe time (m119), 1 q-row/lane (scalar m_i/l_i),
// softmax reduce = single shfl_xor(32). All fragment/epilogue algebra
// identical to the shipped gemm128 32x32 path:
//   A/B-frag: row=l31, k = kk*16 + khalf*8 (logical chunk kk*2+khalf,
//   phys = logical ^ (row&7)); D: lane=m, reg g*4+r -> n = 8g+4khalf+r.

using bf16_t = __hip_bfloat16;
typedef __bf16 bf16x8 __attribute__((ext_vector_type(8)));
typedef float f32x4 __attribute__((ext_vector_type(4)));
typedef float f32x16 __attribute__((ext_vector_type(16)));

__device__ __forceinline__ float b2f(bf16_t v) { return __bfloat162float(v); }
__device__ __forceinline__ bf16_t f2b(float v) { return __float2bfloat16(v); }
__device__ __forceinline__ ushort f2bu(float v) { bf16_t b = f2b(v); return *(ushort*)&b; }

// async global->LDS 16B copy (dest = wave base + lane*16 by construction)
__device__ __forceinline__ void glds16(const ushort* g, ushort* l) {
    __builtin_amdgcn_global_load_lds(
        (const __attribute__((address_space(1))) unsigned int*)g,
        (__attribute__((address_space(3))) unsigned int*)l, 16, 0, 0);
}

// tanh-form GELU (overflow-safe), |err vs exact| ~1e-3 << 0.102 threshold
__device__ __forceinline__ float gelu_f(float x) {
    float x2 = x * x;
    float y2 = 1.5957691216057308f * x * fmaf(0.044715f, x2, 1.0f);
    float e = __expf(y2);
    float t = 1.f - 2.f / (e + 1.f);
    return 0.5f * x * (1.f + t);
}

// ---------------------------------------------------------------------------
// Prep mega-kernel: 6 weight transposes + bias concat + X cast. One launch.
// ---------------------------------------------------------------------------
__device__ __forceinline__ void tr_tile(const float* __restrict__ in,
                                        bf16_t* __restrict__ out,
                                        int R, int C, int tx, int ty,
                                        float (*t)[65], int tid)
{
    int r0 = ty * 64, c0 = tx * 64;
    int tr = tid >> 6, tc = tid & 63;
#pragma unroll 4
    for (int i = 0; i < 16; ++i) {
        int r = i * 4 + tr;
        t[r][tc] = in[(size_t)(r0 + r) * C + c0 + tc];
    }
    __syncthreads();
#pragma unroll 4
    for (int i = 0; i < 16; ++i) {
        int r = i * 4 + tr;
        out[(size_t)(c0 + r) * R + r0 + tc] = f2b(t[tc][r]);
    }
}

__global__ __launch_bounds__(256) void prep_kernel(
    const float* __restrict__ WQ, const float* __restrict__ WK,
    const float* __restrict__ WV, const float* __restrict__ WO,
    const float* __restrict__ W1, const float* __restrict__ W2,
    const float* __restrict__ bQ, const float* __restrict__ bK,
    const float* __restrict__ bV, const float* __restrict__ X,
    bf16_t* __restrict__ Wqkv, bf16_t* __restrict__ WOt,
    bf16_t* __restrict__ W1t, bf16_t* __restrict__ W2t,
    float* __restrict__ bcat, bf16_t* __restrict__ Xb)
{
    __shared__ float t[64][65];
    const int blk = blockIdx.x, tid = threadIdx.x;
    if (blk < 576) {
        int m = blk / 144, tt = blk % 144;
        const float* in = (m == 0) ? WQ : (m == 1) ? WK : (m == 2) ? WV : WO;
        bf16_t* out = (m == 0) ? Wqkv : (m == 1) ? Wqkv + 589824
                    : (m == 2) ? Wqkv + 1179648 : WOt;
        tr_tile(in, out, 768, 768, tt % 12, tt / 12, t, tid);
    } else if (blk < 1152) {
        int tt = blk - 576;
        tr_tile(W1, W1t, 768, 3072, tt % 48, tt / 48, t, tid);
    } else if (blk < 1728) {
        int tt = blk - 1152;
        tr_tile(W2, W2t, 3072, 768, tt % 12, tt / 12, t, tid);
    } else if (blk == 1728) {
        for (int i = tid; i < 2304; i += 256)
            bcat[i] = (i < 768) ? bQ[i] : (i < 1536) ? bK[i - 768] : bV[i - 1536];
    } else {
        size_t i = ((size_t)(blk - 1729) * 256 + tid) * 8;
        float4 a = *(const float4*)(X + i);
        float4 b = *(const float4*)(X + i + 4);
#pragma unroll
        for (int j = 0; j < 4; ++j) {
            Xb[i + j]     = f2b(((const float*)&a)[j]);
            Xb[i + 4 + j] = f2b(((const float*)&b)[j]);
        }
    }
}

// ---------------------------------------------------------------------------
// NT GEMM, BK=64, swapped-operand mfma_f32_32x32x16_bf16 (round-10 proven).
// Tile 128 x NTILE x 64, 256 thr = 4 waves; wave quadrant 64 x (NTILE/2).
// Frags: row = lane&31, k = kk*16 + (lane>>5)*8; phys chunk =
// (kk*2 + (lane>>5)) ^ (row&7). D (swapped): lane = m; reg g*4+r ->
// n = 8g + 4*(lane>>5) + r.
// EPI: 1 bias+GELU->bf16 | 2 bias+res(fp32,ld=ldc)->bf16
//      5 bias+res(bf16,ld=ldc)->fp32 | 6 bias, segmented QKV.
// ---------------------------------------------------------------------------
template <int EPI, int NTILE>
__global__ __launch_bounds__(256) void gemm128(
    const bf16_t* __restrict__ A, const bf16_t* __restrict__ Bt,
    const float* __restrict__ bias, const void* __restrict__ res,
    void* __restrict__ Cv, int K, int lda, int ldb, int ldc)
{
    __shared__ ushort lA[128 * 64];
    __shared__ ushort lB[NTILE * 64];
    constexpr int NI = NTILE / 64;           // 32x32 n-subtiles per wave
    const int tid = threadIdx.x;
    const int l = tid & 63, w = tid >> 6;
    const int l31 = l & 31, khalf = l >> 5;  // frag row / k-half
    const int m0 = blockIdx.x * 128, n0 = blockIdx.y * NTILE;

    const int srow = tid >> 3;
    const int sg = (((tid & 7) ^ (srow & 7)) << 3);
    const ushort* gA = (const ushort*)A + (size_t)(m0 + srow) * lda + sg;
    const ushort* gB = (const ushort*)Bt + (size_t)(n0 + srow) * ldb + sg;
    ushort* dA = lA + tid * 8;
    ushort* dB = lB + tid * 8;

    f32x16 acc[2][NI] = {};
    const int arow = (w & 1) * 64;
    const int brow = (w >> 1) * (NTILE / 2);

    for (int k0 = 0; k0 < K; k0 += 64) {
        __syncthreads();
        glds16(gA + k0,                      dA);
        glds16(gA + k0 + (size_t)32 * lda,   dA + 2048);
        glds16(gA + k0 + (size_t)64 * lda,   dA + 4096);
        glds16(gA + k0 + (size_t)96 * lda,   dA + 6144);
        glds16(gB + k0,                      dB);
        glds16(gB + k0 + (size_t)32 * ldb,   dB + 2048);
        if constexpr (NTILE == 128) {
            glds16(gB + k0 + (size_t)64 * ldb, dB + 4096);
            glds16(gB + k0 + (size_t)96 * ldb, dB + 6144);
        }
        __syncthreads();
#pragma unroll
        for (int kk = 0; kk < 4; ++kk) {
            const int pc = (((kk * 2 + khalf) ^ (l31 & 7)) << 3);
            bf16x8 bfr[NI];
#pragma unroll
            for (int ni = 0; ni < NI; ++ni)
                bfr[ni] = *(const bf16x8*)&lB[(brow + ni * 32 + l31) * 64 + pc];
#pragma unroll
            for (int mi = 0; mi < 2; ++mi) {
                bf16x8 afr = *(const bf16x8*)&lA[(arow + mi * 32 + l31) * 64 + pc];
#pragma unroll
                for (int ni = 0; ni < NI; ++ni)   // SWAPPED: D lane=m, regs=n
                    acc[mi][ni] = __builtin_amdgcn_mfma_f32_32x32x16_bf16(bfr[ni], afr, acc[mi][ni], 0, 0, 0);
            }
        }
    }

    // Epilogue: m = arow + mi*32 + l31; reg g*4+r -> n = ni*32 + 8g + 4*khalf + r
#pragma unroll
    for (int mi = 0; mi < 2; ++mi) {
        int m = m0 + arow + mi * 32 + l31;
#pragma unroll
        for (int ni = 0; ni < NI; ++ni) {
#pragma unroll
            for (int g = 0; g < 4; ++g) {
                int nb = n0 + brow + ni * 32 + 8 * g + 4 * khalf;  // 4 consecutive n
                float4 bv4 = *(const float4*)&bias[nb];
                float v[4];
#pragma unroll
                for (int r = 0; r < 4; ++r) v[r] = acc[mi][ni][g * 4 + r] + ((const float*)&bv4)[r];
                if constexpr (EPI == 1) {
#pragma unroll
                    for (int r = 0; r < 4; ++r) v[r] = gelu_f(v[r]);
                } else if constexpr (EPI == 2) {
                    float4 r4 = *(const float4*)&((const float*)res)[(size_t)m * ldc + nb];
#pragma unroll
                    for (int r = 0; r < 4; ++r) v[r] += ((const float*)&r4)[r];
                } else if constexpr (EPI == 5) {
                    ushort4 rb = *(const ushort4*)&((const ushort*)res)[(size_t)m * ldc + nb];
#pragma unroll
                    for (int r = 0; r < 4; ++r) v[r] += b2f(*(const bf16_t*)&((const ushort*)&rb)[r]);
                }
                if constexpr (EPI == 5) {
                    *(float4*)&((float*)Cv)[(size_t)m * ldc + nb] = make_float4(v[0], v[1], v[2], v[3]);
                } else {
                    ushort4 st;
                    st.x = f2bu(v[0]); st.y = f2bu(v[1]); st.z = f2bu(v[2]); st.w = f2bu(v[3]);
                    if constexpr (EPI == 6) {
                        int seg = n0 / 768;      // block-uniform (768 % NTILE == 0)
                        int nloc = (n0 % 768) + brow + ni * 32 + 8 * g + 4 * khalf;
                        if (seg < 2) {
                            bf16_t* Cseg = (bf16_t*)Cv + (size_t)seg * 6291456;
                            *(ushort4*)&((ushort*)Cseg)[(size_t)m * 768 + nloc] = st;
                        } else {
                            // V segment -> Vt[h][d][s'] via faithful flat reshape:
                            // fb = (m&511)*768 + nloc; a=fb>>15; s'=(fb>>6)&511; d=fb&63.
                            ushort* vt = (ushort*)res;
                            int fb = (m & 511) * 768 + nloc;
                            int h = (m >> 9) * 12 + (fb >> 15);
                            int d = fb & 63;
                            int s = (fb >> 6) & 511;
                            ushort* vh = vt + (size_t)h * 32768 + s;
                            vh[(size_t)(d + 0) * 512] = st.x;
                            vh[(size_t)(d + 1) * 512] = st.y;
                            vh[(size_t)(d + 2) * 512] = st.z;
                            vh[(size_t)(d + 3) * 512] = st.w;
                        }
                    } else {
                        *(ushort4*)&((ushort*)Cv)[(size_t)m * ldc + nb] = st;
                    }
                }
            }
        }
    }
}

// ---------------------------------------------------------------------------
// Flash attention, Q-tile 128, swapped-operand 32x32x16 MFMA (round 16).
// One block = (q-tile 128, head); wave w owns q rows w*32 + l31 (ONE row
// per lane; lanes l31 / l31+32 hold the two khalf column-subsets).
// S=512 D=64, 8 K-tiles; P via lP[128][72]; Z in-place over Q.
// ---------------------------------------------------------------------------
__global__ __launch_bounds__(256) void flash_kernel(
    const bf16_t* __restrict__ Q, const bf16_t* __restrict__ Kx,
    const bf16_t* __restrict__ Vt, const int* __restrict__ mask,
    bf16_t* __restrict__ Z)
{
    __shared__ ushort lK[64 * 64];
    __shared__ ushort lV[64 * 64];
    __shared__ ushort lP[128 * 72];

    const int h = blockIdx.y;
    const int q0 = blockIdx.x * 128;
    const ushort* Qh = (const ushort*)Q + (size_t)h * 32768;
    const ushort* Kh = (const ushort*)Kx + (size_t)h * 32768;
    const ushort* Vh = (const ushort*)Vt + (size_t)h * 32768;   // [64][512]
    const int* mk = mask + (h / 12) * 512;
    ushort* Zh = (ushort*)Z + (size_t)h * 32768;

    const int tid = threadIdx.x;
    const int l = tid & 63, w = tid >> 6;
    const int l31 = l & 31, khalf = l >> 5;

    // Q A-frags from global (row-major): row = qrow, k = kk*16 + khalf*8
    const int qrow = q0 + w * 32 + l31;
    bf16x8 qfr[4];
#pragma unroll
    for (int kk = 0; kk < 4; ++kk)
        qfr[kk] = *(const bf16x8*)(Qh + (size_t)qrow * 64 + kk * 16 + khalf * 8);

    const int c8p = tid & 7;
    const int kr0 = tid >> 3;
    float m_i = -1e30f, l_i = 0.f;
    f32x16 o4[2] = {};
    const int prow = (w * 32 + l31) * 72;

    for (int kt = 0; kt < 8; ++kt) {
#pragma unroll
        for (int p = 0; p < 2; ++p) {
            int row = kr0 + p * 32;
            int c8l = c8p ^ (row & 7);
            glds16(Kh + (size_t)(kt * 64 + row) * 64 + c8l * 8, lK + (p * 256 + tid) * 8);
            glds16(Vh + (size_t)row * 512 + kt * 64 + c8l * 8, lV + (p * 256 + tid) * 8);
        }
        __syncthreads();

        // QK^T: s4[nt] covers k = nt*32 + (8g + 4khalf + r)
        f32x16 s4[2] = {};
#pragma unroll
        for (int kk = 0; kk < 4; ++kk) {
            const int pc = (((kk * 2 + khalf) ^ (l31 & 7)) << 3);
#pragma unroll
            for (int nt = 0; nt < 2; ++nt) {
                bf16x8 kfr = *(const bf16x8*)&lK[(nt * 32 + l31) * 64 + pc];
                s4[nt] = __builtin_amdgcn_mfma_f32_32x32x16_bf16(kfr, qfr[kk], s4[nt], 0, 0, 0);
            }
        }

        // mask + scale + row-max (in place in s4)
        float rm = -1e30f;
#pragma unroll
        for (int nt = 0; nt < 2; ++nt) {
            int4 mg[4];
#pragma unroll
            for (int g = 0; g < 4; ++g)
                mg[g] = *(const int4*)&mk[kt * 64 + nt * 32 + 8 * g + 4 * khalf];
#pragma unroll
            for (int g = 0; g < 4; ++g)
#pragma unroll
                for (int r = 0; r < 4; ++r) {
                    float v = (((const int*)&mg[g])[r] == 0) ? -1e30f : s4[nt][g * 4 + r] * 0.125f;
                    s4[nt][g * 4 + r] = v;
                    rm = fmaxf(rm, v);
                }
        }
        rm = fmaxf(rm, __shfl_xor(rm, 32));   // combine khalf pair -> full row
        float mn = fmaxf(m_i, rm);
        float al = __expf(m_i - mn);
        float rs = 0.f;
#pragma unroll
        for (int nt = 0; nt < 2; ++nt)
#pragma unroll
            for (int j = 0; j < 16; ++j) {
                float e = __expf(s4[nt][j] - mn);
                s4[nt][j] = e;
                rs += e;
            }
        rs += __shfl_xor(rs, 32);
        l_i = l_i * al + rs;
        m_i = mn;
#pragma unroll
        for (int dt = 0; dt < 2; ++dt)
#pragma unroll
            for (int j = 0; j < 16; ++j) o4[dt][j] *= al;

        // P -> LDS: row = qrow-local, col k = nt*32 + 8g + 4khalf (+r)
#pragma unroll
        for (int nt = 0; nt < 2; ++nt)
#pragma unroll
            for (int g = 0; g < 4; ++g) {
                ushort4 st;
                st.x = f2bu(s4[nt][g * 4 + 0]); st.y = f2bu(s4[nt][g * 4 + 1]);
                st.z = f2bu(s4[nt][g * 4 + 2]); st.w = f2bu(s4[nt][g * 4 + 3]);
                *(ushort4*)&lP[prow + nt * 32 + 8 * g + 4 * khalf] = st;
            }
        __syncthreads();

        // PV: o4[dt] covers d = dt*32 + (8g + 4khalf + r)
#pragma unroll
        for (int kk = 0; kk < 4; ++kk) {
            bf16x8 pafr = *(const bf16x8*)&lP[prow + kk * 16 + khalf * 8];
            const int pc = (((kk * 2 + khalf) ^ (l31 & 7)) << 3);
#pragma unroll
            for (int dt = 0; dt < 2; ++dt) {
                bf16x8 vfr = *(const bf16x8*)&lV[(dt * 32 + l31) * 64 + pc];
                o4[dt] = __builtin_amdgcn_mfma_f32_32x32x16_bf16(vfr, pafr, o4[dt], 0, 0, 0);
            }
        }
        __syncthreads();
    }

    float inv = 1.f / l_i;
#pragma unroll
    for (int dt = 0; dt < 2; ++dt)
#pragma unroll
        for (int g = 0; g < 4; ++g) {
            ushort4 st;
            st.x = f2bu(o4[dt][g * 4 + 0] * inv); st.y = f2bu(o4[dt][g * 4 + 1] * inv);
            st.z = f2bu(o4[dt][g * 4 + 2] * inv); st.w = f2bu(o4[dt][g * 4 + 3] * inv);
            *(ushort4*)&Zh[(size_t)qrow * 64 + dt * 32 + 8 * g + 4 * khalf] = st;
        }
}

// ---------------------------------------------------------------------------
// LayerNorm over H=768, one block per row, fp32 stats. In-place safe.
// ---------------------------------------------------------------------------
__device__ __forceinline__ float to_f(float v)  { return v; }
__device__ __forceinline__ float to_f(bf16_t v) { return b2f(v); }
__device__ __forceinline__ void from_f(float& d, float v)  { d = v; }
__device__ __forceinline__ void from_f(bf16_t& d, float v) { d = f2b(v); }

template <typename TI, typename TO>
__global__ __launch_bounds__(256) void layernorm_kernel(
    const TI* __restrict__ X, const float* __restrict__ w,
    const float* __restrict__ b, TO* __restrict__ out)
{
    const TI* x = X + (size_t)blockIdx.x * 768;
    TO* o = out + (size_t)blockIdx.x * 768;
    int t = threadIdx.x;
    float v[3];
    float s = 0.f, sq = 0.f;
#pragma unroll
    for (int i = 0; i < 3; ++i) {
        v[i] = to_f(x[t + i * 256]);
        s += v[i]; sq += v[i] * v[i];
    }
#pragma unroll
    for (int off = 32; off; off >>= 1) { s += __shfl_xor(s, off); sq += __shfl_xor(sq, off); }
    __shared__ float s1[4], s2[4];
    int wave = t >> 6, lane = t & 63;
    if (lane == 0) { s1[wave] = s; s2[wave] = sq; }
    __syncthreads();
    s  = s1[0] + s1[1] + s1[2] + s1[3];
    sq = s2[0] + s2[1] + s2[2] + s2[3];
    float mu  = s * (1.f / 768.f);
    float var = sq * (1.f / 768.f) - mu * mu;
    float rs  = rsqrtf(var + 1e-5f);
#pragma unroll
    for (int i = 0; i < 3; ++i)
        from_f(o[t + i * 256], (v[i] - mu) * rs * w[t + i * 256] + b[t + i * 256]);
}

// ---------------------------------------------------------------------------
extern "C" void kernel_launch(void* const* d_in, const int* in_sizes, int n_in,
                              void* d_out, int out_size, void* d_ws, size_t ws_size,
                              hipStream_t stream)
{
    const float* X    = (const float*)d_in[0];
    const int*   mask = (const int*)  d_in[1];
    const float* WQ   = (const float*)d_in[2];
    const float* bQ   = (const float*)d_in[3];
    const float* WK   = (const float*)d_in[4];
    const float* bK   = (const float*)d_in[5];
    const float* WV   = (const float*)d_in[6];
    const float* bV   = (const float*)d_in[7];
    const float* WO   = (const float*)d_in[8];
    const float* bO   = (const float*)d_in[9];
    const float* ln1w = (const float*)d_in[10];
    const float* ln1b = (const float*)d_in[11];
    const float* W1   = (const float*)d_in[12];
    const float* b1   = (const float*)d_in[13];
    const float* W2   = (const float*)d_in[14];
    const float* b2   = (const float*)d_in[15];
    const float* ln2w = (const float*)d_in[16];
    const float* ln2b = (const float*)d_in[17];
    float* out = (float*)d_out;

    // ---- workspace (bf16 elems; total 38,539,776 = 77.1 MB) ----
    bf16_t* ws   = (bf16_t*)d_ws;
    bf16_t* Wqkv = ws;                        // [2304][768] (WQt|WKt|WVt)
    bf16_t* WOt  = Wqkv + 1769472;            // [768][768]
    bf16_t* W1t  = WOt + 589824;              // [3072][768]
    bf16_t* W2t  = W1t + 2359296;             // [768][3072]
    float*  bcat = (float*)(W2t + 2359296);   // fp32[2304] (= 4608 bf16)
    bf16_t* Qb   = W2t + 2359296 + 4608;      // packed [8192][768]; Q,K consecutive (EPI 6)
    bf16_t* Kb   = Qb + 6291456;
    bf16_t* Vb   = Kb + 6291456;              // (layout hold)
    bf16_t* Xb   = Vb + 6291456;              // bf16 X (dead after QKV; Y1 alias)
    bf16_t* Vt   = Xb + 6291456;              // per-head V^T [192][64][512], from QKV epilogue
    // aliases (dead-before-write):
    bf16_t* Zb = Qb;   // flash writes Z in-place over Q
    bf16_t* Y1 = Xb;   // O-proj out (Xb dead after QKV gemm)
    bf16_t* X1 = Qb;   // LN1 out (Qb/Z dead after O-proj)
    bf16_t* Hb = Kb;   // FFN mid [8192][3072] = Kb+Vb+Xb+Vt exactly

    // ---- 1. prep ----
    prep_kernel<<<4801, 256, 0, stream>>>(WQ, WK, WV, WO, W1, W2, bQ, bK, bV, X,
                                          Wqkv, WOt, W1t, W2t, bcat, Xb);

    // ---- 2. fused QKV projection -> packed Q/K + transposed Vt ----
    gemm128<6, 128><<<dim3(64, 18), 256, 0, stream>>>(Xb, Wqkv, bcat, Vt, Qb,
                                                      768, 768, 768, 768);

    // ---- 3. flash attention (Q-tile 128, 32x32 MFMA), Z in-place over Q ----
    flash_kernel<<<dim3(4, 192), 256, 0, stream>>>(Qb, Kb, Vt, mask, Zb);

    // ---- 4. O-projection + fp32 residual -> Y1, LN1 -> X1 ----
    gemm128<2, 64><<<dim3(64, 12), 256, 0, stream>>>(Zb, WOt, bO, X, Y1,
                                                     768, 768, 768, 768);
    layernorm_kernel<bf16_t, bf16_t><<<8192, 256, 0, stream>>>(Y1, ln1w, ln1b, X1);

    // ---- 5. FFN ----
    gemm128<1, 128><<<dim3(64, 24), 256, 0, stream>>>(X1, W1t, b1, nullptr, Hb,
                                                      768, 768, 768, 3072);
    gemm128<5, 64><<<dim3(64, 12), 256, 0, stream>>>(Hb, W2t, b2, X1, out,
                                                     3072, 3072, 3072, 768);
    layernorm_kernel<float, float><<<8192, 256, 0, stream>>>(out, ln2w, ln2b, out);
}